// Round 13
// baseline (756.278 us; speedup 1.0000x reference)
//
#include <hip/hip_runtime.h>

// n must be <= 256*1024 for the bucket scheme (bucket = dst >> 10, B <= 256)
// and for the 4B edge packing ((dst&1023)<<18 | src, src < 2^18).

// ---------------- CSR build: tp (small, 200K edges) — old path ----------------

__global__ __launch_bounds__(256) void hist_tp_kernel(
    const int* __restrict__ ei_tp, int E_tp, int* __restrict__ deg_tp)
{
    int i = blockIdx.x * 256 + threadIdx.x;
    if (i < E_tp) atomicAdd(&deg_tp[ei_tp[E_tp + i]], 1);
}

__global__ __launch_bounds__(256) void alloc_tp_kernel(
    int n, const int* __restrict__ deg_tp,
    int* __restrict__ row_tp, int* __restrict__ next_tp, int* __restrict__ ctr)
{
    int i = blockIdx.x * 256 + threadIdx.x;
    if (i >= n) return;
    int d = deg_tp[i];
    int r = atomicAdd(&ctr[0], d);
    row_tp[i] = r; next_tp[i] = r;
}

__global__ __launch_bounds__(256) void fill_tp_kernel(
    const int* __restrict__ ei_tp, int E_tp,
    int* __restrict__ next_tp, int* __restrict__ col_tp)
{
    int i = blockIdx.x * 256 + threadIdx.x;
    if (i >= E_tp) return;
    int src = ei_tp[i];
    int dst = ei_tp[E_tp + i];
    col_tp[atomicAdd(&next_tp[dst], 1)] = src;
}

// ---------------- CSR build: it (3.2M edges) — two-level multisplit ----------------

__global__ __launch_bounds__(256) void bucket_count_kernel(
    const int* __restrict__ ei_it, int E_it, int B, int* __restrict__ bcnt)
{
    __shared__ int h[256];
    h[threadIdx.x] = 0;
    __syncthreads();
    const int stride = gridDim.x * 256;
    for (int i = blockIdx.x * 256 + threadIdx.x; i < E_it; i += stride)
        atomicAdd(&h[ei_it[E_it + i] >> 10], 1);
    __syncthreads();
    int v = h[threadIdx.x];
    if (threadIdx.x < B && v) atomicAdd(&bcnt[threadIdx.x], v);
}

__global__ __launch_bounds__(256) void bucket_prefix_kernel(
    int B, const int* __restrict__ bcnt, int* __restrict__ bbase, int* __restrict__ bcursor)
{
    __shared__ int s[256];
    const int t = threadIdx.x;
    s[t] = (t < B) ? bcnt[t] : 0;
    __syncthreads();
    for (int off = 1; off < 256; off <<= 1) {
        int v = (t >= off) ? s[t - off] : 0;
        __syncthreads();
        if (t >= off) s[t] += v;
        __syncthreads();
    }
    if (t == 0) bbase[0] = 0;
    if (t < B) {
        bbase[t + 1] = s[t];
        bcursor[t] = s[t] - bcnt[t];
    }
}

// Block-local LDS multisplit: histogram -> block prefix -> one global cursor
// bump per bucket -> LDS scatter sorted by bucket -> coalesced packed write-out.

#define MS_E 4096

__global__ __launch_bounds__(256) void multisplit_kernel(
    const int* __restrict__ ei_it, int E_it,
    int* __restrict__ bcursor, unsigned* __restrict__ ebuf)
{
    __shared__ int cnt[256];
    __shared__ int lstart[256];
    __shared__ int gbase[256];
    __shared__ int lnext[256];
    __shared__ unsigned sbuf[MS_E];
    __shared__ unsigned char sbk[MS_E];

    const int t = threadIdx.x;
    const int base = blockIdx.x * MS_E;
    const int m = min(MS_E, E_it - base);

    cnt[t] = 0;
    __syncthreads();

    for (int i = t; i < m; i += 256)
        atomicAdd(&cnt[ei_it[E_it + base + i] >> 10], 1);
    __syncthreads();

    const int c = cnt[t];
    lnext[t] = c;
    __syncthreads();
    for (int off = 1; off < 256; off <<= 1) {
        int v = (t >= off) ? lnext[t - off] : 0;
        __syncthreads();
        if (t >= off) lnext[t] += v;
        __syncthreads();
    }
    const int ex = lnext[t] - c;
    lstart[t] = ex;
    if (c) gbase[t] = atomicAdd(&bcursor[t], c);
    lnext[t] = ex;
    __syncthreads();

    for (int i = t; i < m; i += 256) {
        const int src = ei_it[base + i];
        const int dst = ei_it[E_it + base + i];
        const int bk = dst >> 10;
        const int pos = atomicAdd(&lnext[bk], 1);
        sbuf[pos] = ((unsigned)(dst & 1023) << 18) | (unsigned)src;
        sbk[pos] = (unsigned char)bk;
    }
    __syncthreads();

    for (int i = t; i < m; i += 256) {
        const int bk = sbk[i];
        ebuf[gbase[bk] + (i - lstart[bk])] = sbuf[i];
    }
}

__global__ __launch_bounds__(256) void csr_it_kernel(
    int n, const unsigned* __restrict__ ebuf, const int* __restrict__ bbase,
    int* __restrict__ row_it, int* __restrict__ deg_it,
    float* __restrict__ inv_cnt, int* __restrict__ col_it)
{
    __shared__ int ldeg[1024];
    __shared__ int lnext[1024];
    __shared__ int lpart[256];
    const int b = blockIdx.x;
    const int t = threadIdx.x;
    const int node_lo = b << 10;
    const int nn = min(1024, n - node_lo);
    const int e0 = bbase[b], e1 = bbase[b + 1];

    for (int i = t; i < nn; i += 256) ldeg[i] = 0;
    __syncthreads();
    for (int i = e0 + t; i < e1; i += 256)
        atomicAdd(&ldeg[(int)(ebuf[i] >> 18)], 1);
    __syncthreads();

    const int i4 = 4 * t;
    int l0 = (i4     < nn) ? ldeg[i4]     : 0;
    int l1 = (i4 + 1 < nn) ? ldeg[i4 + 1] : 0;
    int l2 = (i4 + 2 < nn) ? ldeg[i4 + 2] : 0;
    int l3 = (i4 + 3 < nn) ? ldeg[i4 + 3] : 0;
    const int lsum = l0 + l1 + l2 + l3;
    lpart[t] = lsum;
    __syncthreads();
    for (int off = 1; off < 256; off <<= 1) {
        int v = (t >= off) ? lpart[t - off] : 0;
        __syncthreads();
        if (t >= off) lpart[t] += v;
        __syncthreads();
    }
    const int ex = lpart[t] - lsum;

    const int p[4] = {ex, ex + l0, ex + l0 + l1, ex + l0 + l1 + l2};
    const int l[4] = {l0, l1, l2, l3};
#pragma unroll
    for (int k = 0; k < 4; k++) {
        int i = i4 + k;
        if (i < nn) {
            lnext[i] = p[k];
            row_it[node_lo + i]  = e0 + p[k];
            deg_it[node_lo + i]  = l[k];
            inv_cnt[node_lo + i] = 1.0f / (float)max(l[k], 1);
        }
    }
    __syncthreads();
    for (int i = e0 + t; i < e1; i += 256) {
        const unsigned v = ebuf[i];
        const int dstl = (int)(v >> 18);
        const int pos  = atomicAdd(&lnext[dstl], 1);
        col_it[e0 + pos] = (int)(v & 0x3FFFFu);
    }
}

// ---------------- Weight prep: Wcat = [Wrel0 | Wrel1 | Wroot0+Wroot1], bias sums ----
// Layout (floats): head W 18x32 @ 0; layer l W 96x32 @ 576 + l*3072;
// head bias 32 @ 12864; layer l bias 32 @ 12896 + l*32. Total 13024.

__global__ __launch_bounds__(256) void prep_weights_kernel(
    const float* __restrict__ W0_rel, const float* __restrict__ W0_root,
    const float* __restrict__ b0, const float* __restrict__ W_rel,
    const float* __restrict__ W_root, const float* __restrict__ b,
    float* __restrict__ wcat)
{
    int i = blockIdx.x * 256 + threadIdx.x;
    if (i < 576) {
        int k = i >> 5, j = i & 31;
        float v;
        if (k < 6)       v = W0_rel[k * 32 + j];
        else if (k < 12) v = W0_rel[192 + (k - 6) * 32 + j];
        else             v = W0_root[(k - 12) * 32 + j] + W0_root[192 + (k - 12) * 32 + j];
        wcat[i] = v;
    } else if (i < 576 + 4 * 3072) {
        int t = i - 576;
        int l = t / 3072, r = t % 3072;
        int k = r >> 5, j = r & 31;
        const float* Wr = W_rel  + l * 2048;
        const float* Wt = W_root + l * 2048;
        float v;
        if (k < 32)      v = Wr[k * 32 + j];
        else if (k < 64) v = Wr[1024 + (k - 32) * 32 + j];
        else             v = Wt[(k - 64) * 32 + j] + Wt[1024 + (k - 64) * 32 + j];
        wcat[i] = v;
    } else if (i < 13024) {
        int t = i - 12864;
        if (t < 32) wcat[i] = b0[t] + b0[32 + t];
        else {
            int l = (t - 32) >> 5, j = (t - 32) & 31;
            wcat[i] = b[l * 64 + j] + b[l * 64 + 32 + j];
        }
    }
}

// ---------------- Fused layer: aggregation + GEMM + resid + ReLU ----------------
// 128-thread blocks (2 waves), LDS 6144 B/block, __launch_bounds__(128, 4).
// Occupancy ladder (measured): no hint 38%/97us; (128,8) spilled (budget 32),
// 196us; (128,4) 49%/88us; (128,5) no change (49%/88us) — residency is capped
// by the combined VGPR+AGPR footprint (w[48] parks in accvgprs), so further
// occupancy pushes are dead. This version instead doubles memory-level
// parallelism per wave: the intersects gather is unrolled 8-deep (16
// outstanding VMEM/wave vs 8; vmcnt cap is 63). Throughput of this
// latency-bound gather ~ waves x unroll-depth: 16x8 = 128 "units" vs agg32's
// 23x4 = 92 at 71us. VGPR headroom: 48 + 16 (4 extra float4 in flight) = 64,
// exactly the (128,4) budget. Revert criterion: WRITE_SIZE >> 25MB (spill).
// Phase 1 (per wave, 8 nodes, 8 lanes/node): gather-aggregate; park 96
// per-node inputs (aggA | aggM*ic | hin) in LDS (wave-local; no barrier).
// Phase 2 (same wave, remapped): lane = (col c = lane&31, k-half kh = lane>>5);
// 48 W floats/lane in registers; broadcast ds_read_b128 + FMA; shfl_xor(32)
// half-reduce; bias + resid + ReLU; 128B half-wave store.

__global__ __launch_bounds__(128, 4) void layer_fused_kernel(
    int n, const float* __restrict__ hin,
    const int* __restrict__ row_it, const int* __restrict__ deg_it, const int* __restrict__ col_it,
    const int* __restrict__ row_tp, const int* __restrict__ deg_tp, const int* __restrict__ col_tp,
    const float* __restrict__ inv_cnt,
    const float* __restrict__ Wcat, const float* __restrict__ bias,
    float* __restrict__ hout)
{
    __shared__ __align__(16) float sagg[2][8][96];   // [wave][node][96] = 6144 B

    const int wave = threadIdx.x >> 6;
    const int lane = threadIdx.x & 63;
    const int g = lane >> 3;
    const int q = lane & 7;
    const int c  = lane & 31;
    const int kh = lane >> 5;
    const int nb = (blockIdx.x * 2 + wave) * 8;
    if (nb >= n) return;

    // W tile: this lane's 48 k-rows of column c (half kh). Coalesced 128B rows.
    float w[48];
#pragma unroll
    for (int k = 0; k < 48; k++)
        w[k] = Wcat[(kh * 48 + k) * 32 + c];
    const float bc = bias[c];

    // ---- Phase 1: aggregate ----
    const int node = nb + g;
    if (node < n) {
        const float4 hq = *(const float4*)&hin[(size_t)node * 32 + q * 4];
        float4 aA = make_float4(0.f, 0.f, 0.f, 0.f);
        float4 aM = make_float4(0.f, 0.f, 0.f, 0.f);

        {
            const int rs = row_tp[node], d = deg_tp[node];
            for (int e = 0; e < d; e++) {
                const int j = col_tp[rs + e];
                const float4 v = *(const float4*)&hin[(size_t)j * 32 + q * 4];
                aA.x += v.x; aA.y += v.y; aA.z += v.z; aA.w += v.w;
            }
        }
        {
            const int rs = row_it[node], d = deg_it[node];
            int e = 0;
            for (; e + 7 < d; e += 8) {
                int j[8];
#pragma unroll
                for (int u = 0; u < 8; u++) j[u] = col_it[rs + e + u];
                float4 v[8];
#pragma unroll
                for (int u = 0; u < 8; u++)
                    v[u] = *(const float4*)&hin[(size_t)j[u] * 32 + q * 4];
#pragma unroll
                for (int u = 0; u < 8; u++) {
                    aM.x += v[u].x; aM.y += v[u].y;
                    aM.z += v[u].z; aM.w += v[u].w;
                }
            }
            for (; e + 3 < d; e += 4) {
                const int j0 = col_it[rs + e];
                const int j1 = col_it[rs + e + 1];
                const int j2 = col_it[rs + e + 2];
                const int j3 = col_it[rs + e + 3];
                const float4 v0 = *(const float4*)&hin[(size_t)j0 * 32 + q * 4];
                const float4 v1 = *(const float4*)&hin[(size_t)j1 * 32 + q * 4];
                const float4 v2 = *(const float4*)&hin[(size_t)j2 * 32 + q * 4];
                const float4 v3 = *(const float4*)&hin[(size_t)j3 * 32 + q * 4];
                aM.x += (v0.x + v1.x) + (v2.x + v3.x);
                aM.y += (v0.y + v1.y) + (v2.y + v3.y);
                aM.z += (v0.z + v1.z) + (v2.z + v3.z);
                aM.w += (v0.w + v1.w) + (v2.w + v3.w);
            }
            for (; e < d; e++) {
                const int j = col_it[rs + e];
                const float4 v = *(const float4*)&hin[(size_t)j * 32 + q * 4];
                aM.x += v.x; aM.y += v.y; aM.z += v.z; aM.w += v.w;
            }
        }

        const float ic = inv_cnt[node];
        aM.x *= ic; aM.y *= ic; aM.z *= ic; aM.w *= ic;
        *(float4*)&sagg[wave][g][q * 4]      = aA;
        *(float4*)&sagg[wave][g][32 + q * 4] = aM;
        *(float4*)&sagg[wave][g][64 + q * 4] = hq;
    }
    // wave-local LDS write->read: compiler inserts the lgkmcnt wait (alias dep).

    // ---- Phase 2: GEMM over the wave's 8 nodes ----
#pragma unroll
    for (int nd = 0; nd < 8; nd++) {
        if (nb + nd < n) {
            const float* ap = &sagg[wave][nd][kh * 48];
            float acc = 0.f;
#pragma unroll
            for (int kk = 0; kk < 48; kk += 4) {
                const float4 a4 = *(const float4*)(ap + kk);
                acc = fmaf(a4.x, w[kk],     acc);
                acc = fmaf(a4.y, w[kk + 1], acc);
                acc = fmaf(a4.z, w[kk + 2], acc);
                acc = fmaf(a4.w, w[kk + 3], acc);
            }
            acc += __shfl_xor(acc, 32, 64);
            if (kh == 0) {
                const float r = fmaxf(acc + bc + sagg[wave][nd][64 + c], 0.f);
                hout[(size_t)(nb + nd) * 32 + c] = r;
            }
        }
    }
}

// ---------------- Aggregation (C=6, head): 8 nodes per wave ----------------

__global__ __launch_bounds__(256, 8) void agg6_kernel(
    int n, const float* __restrict__ hin,
    const int* __restrict__ row_it, const int* __restrict__ deg_it, const int* __restrict__ col_it,
    const int* __restrict__ row_tp, const int* __restrict__ deg_tp, const int* __restrict__ col_tp,
    const float* __restrict__ inv_cnt, float* __restrict__ agg)
{
    const int wave = threadIdx.x >> 6;
    const int lane = threadIdx.x & 63;
    const int g = lane >> 3;
    const int c = lane & 7;
    const int cc = (c < 6) ? c : 0;
    const int node = (blockIdx.x * 4 + wave) * 8 + g;
    if (node >= n) return;

    float aA = 0.f, aM = 0.f;
    {
        const int rs = row_tp[node], d = deg_tp[node];
        for (int e = 0; e < d; e++) {
            const int j = col_tp[rs + e];
            aA += hin[(size_t)j * 6 + cc];
        }
    }
    {
        const int rs = row_it[node], d = deg_it[node];
        int e = 0;
        for (; e + 3 < d; e += 4) {
            const int j0 = col_it[rs + e];
            const int j1 = col_it[rs + e + 1];
            const int j2 = col_it[rs + e + 2];
            const int j3 = col_it[rs + e + 3];
            aM += (hin[(size_t)j0 * 6 + cc] + hin[(size_t)j1 * 6 + cc])
                + (hin[(size_t)j2 * 6 + cc] + hin[(size_t)j3 * 6 + cc]);
        }
        for (; e < d; e++) {
            const int j = col_it[rs + e];
            aM += hin[(size_t)j * 6 + cc];
        }
    }

    if (c < 6) {
        agg[(size_t)node * 12 + c]     = aA;
        agg[(size_t)node * 12 + 6 + c] = aM * inv_cnt[node];
    }
}

// ---------------- Head GEMM (CI=6), register version ----------------

template <int CI, bool RESID>
__global__ __launch_bounds__(256) void gemm_reg_kernel(
    int n, const float* __restrict__ agg, const float* __restrict__ hin,
    const float* __restrict__ Wcat, const float* __restrict__ bias,
    float* __restrict__ hout)
{
    const int node = blockIdx.x * 256 + threadIdx.x;
    if (node >= n) return;

    float acc[32];
#pragma unroll
    for (int j = 0; j < 32; j++) acc[j] = bias[j];

    if constexpr (CI == 32) {
        const float* arow = agg + (size_t)node * 64;
#pragma unroll
        for (int c = 0; c < 8; c++) {
            const float4 a0 = *(const float4*)(arow + c * 8);
            const float4 a1 = *(const float4*)(arow + c * 8 + 4);
            const float av[8] = {a0.x, a0.y, a0.z, a0.w, a1.x, a1.y, a1.z, a1.w};
#pragma unroll
            for (int kk = 0; kk < 8; kk++) {
                const float* wr = Wcat + (c * 8 + kk) * 32;
#pragma unroll
                for (int j = 0; j < 32; j++) acc[j] = fmaf(av[kk], wr[j], acc[j]);
            }
        }
        const float* hrow = hin + (size_t)node * 32;
#pragma unroll
        for (int c = 0; c < 4; c++) {
            const float4 a0 = *(const float4*)(hrow + c * 8);
            const float4 a1 = *(const float4*)(hrow + c * 8 + 4);
            const float av[8] = {a0.x, a0.y, a0.z, a0.w, a1.x, a1.y, a1.z, a1.w};
#pragma unroll
            for (int kk = 0; kk < 8; kk++) {
                const float* wr = Wcat + (64 + c * 8 + kk) * 32;
#pragma unroll
                for (int j = 0; j < 32; j++) acc[j] = fmaf(av[kk], wr[j], acc[j]);
            }
            if (RESID) {
#pragma unroll
                for (int kk = 0; kk < 8; kk++) acc[c * 8 + kk] += av[kk];
            }
        }
    } else {  // CI == 6, K = 18
        const float* arow = agg + (size_t)node * 12;
#pragma unroll
        for (int k = 0; k < 12; k++) {
            const float a = arow[k];
            const float* wr = Wcat + k * 32;
#pragma unroll
            for (int j = 0; j < 32; j++) acc[j] = fmaf(a, wr[j], acc[j]);
        }
        const float* xrow = hin + (size_t)node * 6;
#pragma unroll
        for (int k = 0; k < 6; k++) {
            const float a = xrow[k];
            const float* wr = Wcat + (12 + k) * 32;
#pragma unroll
            for (int j = 0; j < 32; j++) acc[j] = fmaf(a, wr[j], acc[j]);
        }
    }

#pragma unroll
    for (int j = 0; j < 32; j++) acc[j] = fmaxf(acc[j], 0.f);
    float* orow = hout + (size_t)node * 32;
#pragma unroll
    for (int j = 0; j < 32; j += 4)
        *(float4*)(orow + j) = make_float4(acc[j], acc[j + 1], acc[j + 2], acc[j + 3]);
}

// ---------------- Final linear: W-in-registers, node-streaming ----------------

__global__ __launch_bounds__(256) void final_kernel(
    int n, const float* __restrict__ h, const float* __restrict__ Wout,
    const float* __restrict__ bout, float* __restrict__ out)
{
    const int wave = threadIdx.x >> 6;
    const int lane = threadIdx.x & 63;
    const int c2 = lane * 2;  // this lane's 2 output columns

    int node0 = (blockIdx.x * 4 + wave) * 32;
    if (node0 >= n) return;
    const int node_hi = min(node0 + 32, n);

    float2 w[32];
#pragma unroll
    for (int k = 0; k < 32; k++)
        w[k] = *(const float2*)(Wout + k * 128 + c2);
    const float2 bb = *(const float2*)(bout + c2);

    const float* hp = h + (size_t)node0 * 32 + lane;
    float hv = *hp;

    for (; node0 < node_hi; node0 += 2) {
        float hvn = 0.f;
        if (node0 + 2 < node_hi) hvn = hp[64];
        hp += 64;

        float a0 = bb.x, a1 = bb.y;
        float d0 = bb.x, d1 = bb.y;
#pragma unroll
        for (int k = 0; k < 32; k++) {
            const float sA = __uint_as_float(
                __builtin_amdgcn_readlane(__float_as_uint(hv), k));
            const float sB = __uint_as_float(
                __builtin_amdgcn_readlane(__float_as_uint(hv), 32 + k));
            a0 = fmaf(sA, w[k].x, a0);
            a1 = fmaf(sA, w[k].y, a1);
            d0 = fmaf(sB, w[k].x, d0);
            d1 = fmaf(sB, w[k].y, d1);
        }

        *(float2*)(out + (size_t)node0 * 128 + c2) = make_float2(a0, a1);
        if (node0 + 1 < n)
            *(float2*)(out + (size_t)(node0 + 1) * 128 + c2) = make_float2(d0, d1);
        hv = hvn;
    }
}

// ---------------- launch ----------------

extern "C" void kernel_launch(void* const* d_in, const int* in_sizes, int n_in,
                              void* d_out, int out_size, void* d_ws, size_t ws_size,
                              hipStream_t stream)
{
    const float* x      = (const float*)d_in[0];
    const int*   ei_tp  = (const int*)d_in[1];
    const int*   ei_it  = (const int*)d_in[2];
    const float* W0_rel  = (const float*)d_in[3];
    const float* W0_root = (const float*)d_in[4];
    const float* b0      = (const float*)d_in[5];
    const float* W_rel   = (const float*)d_in[6];
    const float* W_root  = (const float*)d_in[7];
    const float* b       = (const float*)d_in[8];
    const float* Wout    = (const float*)d_in[9];
    const float* bout    = (const float*)d_in[10];
    float* out = (float*)d_out;

    const int n    = in_sizes[0] / 6;
    const int E_tp = in_sizes[1] / 2;
    const int E_it = in_sizes[2] / 2;
    const int B    = (n + 1023) >> 10;

    float* h0      = (float*)d_ws;
    float* h1      = h0 + (size_t)n * 32;
    int*   deg_it  = (int*)(h1 + (size_t)n * 32);
    int*   row_it  = deg_it + n;
    float* inv_cnt = (float*)(row_it + n);
    int*   deg_tp  = (int*)(inv_cnt + n);
    int*   ctr     = deg_tp + n;
    int*   bcnt    = ctr + 1;
    int*   bbase   = bcnt + 256;
    int*   bcursor = bbase + 257;
    int*   row_tp  = bcursor + 256;
    int*   next_tp = row_tp + n;
    int*   col_it  = next_tp + n;
    int*   col_tp  = col_it + E_it;
    float* wcat    = (float*)(col_tp + E_tp);   // 13024 floats
    unsigned* ebuf = (unsigned*)d_out;
    float* aggbuf  = (float*)d_out;

    hipMemsetAsync(deg_tp, 0, (size_t)(n + 1 + 256) * sizeof(int), stream);

    prep_weights_kernel<<<51, 256, 0, stream>>>(W0_rel, W0_root, b0, W_rel, W_root, b, wcat);

    bucket_count_kernel<<<512, 256, 0, stream>>>(ei_it, E_it, B, bcnt);
    bucket_prefix_kernel<<<1, 256, 0, stream>>>(B, bcnt, bbase, bcursor);
    multisplit_kernel<<<(E_it + MS_E - 1) / MS_E, 256, 0, stream>>>(ei_it, E_it, bcursor, ebuf);
    csr_it_kernel<<<B, 256, 0, stream>>>(n, ebuf, bbase, row_it, deg_it, inv_cnt, col_it);

    hist_tp_kernel<<<(E_tp + 255) / 256, 256, 0, stream>>>(ei_tp, E_tp, deg_tp);
    alloc_tp_kernel<<<(n + 255) / 256, 256, 0, stream>>>(n, deg_tp, row_tp, next_tp, ctr);
    fill_tp_kernel<<<(E_tp + 255) / 256, 256, 0, stream>>>(ei_tp, E_tp, next_tp, col_tp);

    const int agg_blocks = (n + 31) / 32;

    agg6_kernel<<<agg_blocks, 256, 0, stream>>>(n, x, row_it, deg_it, col_it,
                                                row_tp, deg_tp, col_tp, inv_cnt, aggbuf);
    gemm_reg_kernel<6, false><<<(n + 255) / 256, 256, 0, stream>>>(
        n, aggbuf, x, wcat, wcat + 12864, h0);

    float* hin  = h0;
    float* hout = h1;
    for (int l = 0; l < 4; l++) {
        layer_fused_kernel<<<(n + 15) / 16, 128, 0, stream>>>(
            n, hin, row_it, deg_it, col_it, row_tp, deg_tp, col_tp, inv_cnt,
            wcat + 576 + l * 3072, wcat + 12896 + l * 32, hout);
        float* t = hin; hin = hout; hout = t;
    }

    final_kernel<<<(n + 127) / 128, 256, 0, stream>>>(n, hin, Wout, bout, out);
}

// Round 17
// 717.370 us; speedup vs baseline: 1.0542x; 1.0542x over previous
//
#include <hip/hip_runtime.h>

// n must be <= 256*1024 for the bucket scheme (bucket = dst >> 10, B <= 256)
// and for the 4B edge packing ((dst&1023)<<18 | src, src < 2^18).

// ---------------- CSR build: tp (small, 200K edges) — old path ----------------

__global__ __launch_bounds__(256) void hist_tp_kernel(
    const int* __restrict__ ei_tp, int E_tp, int* __restrict__ deg_tp)
{
    int i = blockIdx.x * 256 + threadIdx.x;
    if (i < E_tp) atomicAdd(&deg_tp[ei_tp[E_tp + i]], 1);
}

__global__ __launch_bounds__(256) void alloc_tp_kernel(
    int n, const int* __restrict__ deg_tp,
    int* __restrict__ row_tp, int* __restrict__ next_tp, int* __restrict__ ctr)
{
    int i = blockIdx.x * 256 + threadIdx.x;
    if (i >= n) return;
    int d = deg_tp[i];
    int r = atomicAdd(&ctr[0], d);
    row_tp[i] = r; next_tp[i] = r;
}

__global__ __launch_bounds__(256) void fill_tp_kernel(
    const int* __restrict__ ei_tp, int E_tp,
    int* __restrict__ next_tp, int* __restrict__ col_tp)
{
    int i = blockIdx.x * 256 + threadIdx.x;
    if (i >= E_tp) return;
    int src = ei_tp[i];
    int dst = ei_tp[E_tp + i];
    col_tp[atomicAdd(&next_tp[dst], 1)] = src;
}

// ---------------- CSR build: it (3.2M edges) — two-level multisplit ----------------

__global__ __launch_bounds__(256) void bucket_count_kernel(
    const int* __restrict__ ei_it, int E_it, int B, int* __restrict__ bcnt)
{
    __shared__ int h[256];
    h[threadIdx.x] = 0;
    __syncthreads();
    const int stride = gridDim.x * 256;
    for (int i = blockIdx.x * 256 + threadIdx.x; i < E_it; i += stride)
        atomicAdd(&h[ei_it[E_it + i] >> 10], 1);
    __syncthreads();
    int v = h[threadIdx.x];
    if (threadIdx.x < B && v) atomicAdd(&bcnt[threadIdx.x], v);
}

__global__ __launch_bounds__(256) void bucket_prefix_kernel(
    int B, const int* __restrict__ bcnt, int* __restrict__ bbase, int* __restrict__ bcursor)
{
    __shared__ int s[256];
    const int t = threadIdx.x;
    s[t] = (t < B) ? bcnt[t] : 0;
    __syncthreads();
    for (int off = 1; off < 256; off <<= 1) {
        int v = (t >= off) ? s[t - off] : 0;
        __syncthreads();
        if (t >= off) s[t] += v;
        __syncthreads();
    }
    if (t == 0) bbase[0] = 0;
    if (t < B) {
        bbase[t + 1] = s[t];
        bcursor[t] = s[t] - bcnt[t];
    }
}

// Block-local LDS multisplit: histogram -> block prefix -> one global cursor
// bump per bucket -> LDS scatter sorted by bucket -> coalesced packed write-out.

#define MS_E 4096

__global__ __launch_bounds__(256) void multisplit_kernel(
    const int* __restrict__ ei_it, int E_it,
    int* __restrict__ bcursor, unsigned* __restrict__ ebuf)
{
    __shared__ int cnt[256];
    __shared__ int lstart[256];
    __shared__ int gbase[256];
    __shared__ int lnext[256];
    __shared__ unsigned sbuf[MS_E];
    __shared__ unsigned char sbk[MS_E];

    const int t = threadIdx.x;
    const int base = blockIdx.x * MS_E;
    const int m = min(MS_E, E_it - base);

    cnt[t] = 0;
    __syncthreads();

    for (int i = t; i < m; i += 256)
        atomicAdd(&cnt[ei_it[E_it + base + i] >> 10], 1);
    __syncthreads();

    const int c = cnt[t];
    lnext[t] = c;
    __syncthreads();
    for (int off = 1; off < 256; off <<= 1) {
        int v = (t >= off) ? lnext[t - off] : 0;
        __syncthreads();
        if (t >= off) lnext[t] += v;
        __syncthreads();
    }
    const int ex = lnext[t] - c;
    lstart[t] = ex;
    if (c) gbase[t] = atomicAdd(&bcursor[t], c);
    lnext[t] = ex;
    __syncthreads();

    for (int i = t; i < m; i += 256) {
        const int src = ei_it[base + i];
        const int dst = ei_it[E_it + base + i];
        const int bk = dst >> 10;
        const int pos = atomicAdd(&lnext[bk], 1);
        sbuf[pos] = ((unsigned)(dst & 1023) << 18) | (unsigned)src;
        sbk[pos] = (unsigned char)bk;
    }
    __syncthreads();

    for (int i = t; i < m; i += 256) {
        const int bk = sbk[i];
        ebuf[gbase[bk] + (i - lstart[bk])] = sbuf[i];
    }
}

__global__ __launch_bounds__(256) void csr_it_kernel(
    int n, const unsigned* __restrict__ ebuf, const int* __restrict__ bbase,
    int* __restrict__ row_it, int* __restrict__ deg_it,
    float* __restrict__ inv_cnt, int* __restrict__ col_it)
{
    __shared__ int ldeg[1024];
    __shared__ int lnext[1024];
    __shared__ int lpart[256];
    const int b = blockIdx.x;
    const int t = threadIdx.x;
    const int node_lo = b << 10;
    const int nn = min(1024, n - node_lo);
    const int e0 = bbase[b], e1 = bbase[b + 1];

    for (int i = t; i < nn; i += 256) ldeg[i] = 0;
    __syncthreads();
    for (int i = e0 + t; i < e1; i += 256)
        atomicAdd(&ldeg[(int)(ebuf[i] >> 18)], 1);
    __syncthreads();

    const int i4 = 4 * t;
    int l0 = (i4     < nn) ? ldeg[i4]     : 0;
    int l1 = (i4 + 1 < nn) ? ldeg[i4 + 1] : 0;
    int l2 = (i4 + 2 < nn) ? ldeg[i4 + 2] : 0;
    int l3 = (i4 + 3 < nn) ? ldeg[i4 + 3] : 0;
    const int lsum = l0 + l1 + l2 + l3;
    lpart[t] = lsum;
    __syncthreads();
    for (int off = 1; off < 256; off <<= 1) {
        int v = (t >= off) ? lpart[t - off] : 0;
        __syncthreads();
        if (t >= off) lpart[t] += v;
        __syncthreads();
    }
    const int ex = lpart[t] - lsum;

    const int p[4] = {ex, ex + l0, ex + l0 + l1, ex + l0 + l1 + l2};
    const int l[4] = {l0, l1, l2, l3};
#pragma unroll
    for (int k = 0; k < 4; k++) {
        int i = i4 + k;
        if (i < nn) {
            lnext[i] = p[k];
            row_it[node_lo + i]  = e0 + p[k];
            deg_it[node_lo + i]  = l[k];
            inv_cnt[node_lo + i] = 1.0f / (float)max(l[k], 1);
        }
    }
    __syncthreads();
    for (int i = e0 + t; i < e1; i += 256) {
        const unsigned v = ebuf[i];
        const int dstl = (int)(v >> 18);
        const int pos  = atomicAdd(&lnext[dstl], 1);
        col_it[e0 + pos] = (int)(v & 0x3FFFFu);
    }
}

// ---------------- Weight prep: Wcat = [Wrel0 | Wrel1 | Wroot0+Wroot1], bias sums ----
// Layout (floats): head W 18x32 @ 0; layer l W 96x32 @ 576 + l*3072;
// head bias 32 @ 12864; layer l bias 32 @ 12896 + l*32. Total 13024.

__global__ __launch_bounds__(256) void prep_weights_kernel(
    const float* __restrict__ W0_rel, const float* __restrict__ W0_root,
    const float* __restrict__ b0, const float* __restrict__ W_rel,
    const float* __restrict__ W_root, const float* __restrict__ b,
    float* __restrict__ wcat)
{
    int i = blockIdx.x * 256 + threadIdx.x;
    if (i < 576) {
        int k = i >> 5, j = i & 31;
        float v;
        if (k < 6)       v = W0_rel[k * 32 + j];
        else if (k < 12) v = W0_rel[192 + (k - 6) * 32 + j];
        else             v = W0_root[(k - 12) * 32 + j] + W0_root[192 + (k - 12) * 32 + j];
        wcat[i] = v;
    } else if (i < 576 + 4 * 3072) {
        int t = i - 576;
        int l = t / 3072, r = t % 3072;
        int k = r >> 5, j = r & 31;
        const float* Wr = W_rel  + l * 2048;
        const float* Wt = W_root + l * 2048;
        float v;
        if (k < 32)      v = Wr[k * 32 + j];
        else if (k < 64) v = Wr[1024 + (k - 32) * 32 + j];
        else             v = Wt[(k - 64) * 32 + j] + Wt[1024 + (k - 64) * 32 + j];
        wcat[i] = v;
    } else if (i < 13024) {
        int t = i - 12864;
        if (t < 32) wcat[i] = b0[t] + b0[32 + t];
        else {
            int l = (t - 32) >> 5, j = (t - 32) & 31;
            wcat[i] = b[l * 64 + j] + b[l * 64 + 32 + j];
        }
    }
}

// ---------------- Fused layer: aggregation + GEMM + resid + ReLU (v3) ----------------
// Fix of R13's v2 (which read sagg rows 64..95 out of bounds after dropping hq):
// sagg restored to [2][8][96] per node = aggA(32)|aggM(32)|hq(32); hq is written
// to LDS immediately after its load so its registers retire before the gather.
// Occupancy intent: the W tile (w[24], quarter kq = wave*2+kh of 96 k-rows) and
// bias are loaded AFTER the first barrier — the compiler won't hoist global
// loads above __syncthreads, so phase-1 gather temps (~44 regs) and the W tile
// no longer coexist; target static footprint <= 64 (reg bins {64,128,256}:
// 96->4 waves/SIMD was R11's wall, <=64 -> 8 possible). (128,6): budget 85,
// no spill risk. Phase 2: cross-wave 4-quarter GEMM — both waves compute
// partials for all 16 block nodes (broadcast LDS A-reads, conflict-free),
// part[2][16][32], barrier, wave finalizes its own 8 nodes (resid from sagg).
// LDS: 6144 + 4096 = 10240 B/block.

__global__ __launch_bounds__(128, 6) void layer_fused_kernel(
    int n, const float* __restrict__ hin,
    const int* __restrict__ row_it, const int* __restrict__ deg_it, const int* __restrict__ col_it,
    const int* __restrict__ row_tp, const int* __restrict__ deg_tp, const int* __restrict__ col_tp,
    const float* __restrict__ inv_cnt,
    const float* __restrict__ Wcat, const float* __restrict__ bias,
    float* __restrict__ hout)
{
    __shared__ __align__(16) float sagg[2][8][96];   // [wave][node][aggA|aggM|hq] 6144 B
    __shared__ float part[2][16][32];                // [wave][node][col] 4096 B

    const int wave = threadIdx.x >> 6;
    const int lane = threadIdx.x & 63;
    const int g = lane >> 3;
    const int q = lane & 7;
    const int c  = lane & 31;
    const int kh = lane >> 5;
    const int kq = wave * 2 + kh;          // k-quarter: rows [kq*24, kq*24+24)
    const int nbase = blockIdx.x * 16;     // block's 16 nodes
    if (nbase >= n) return;                // uniform across block

    // ---- Phase 1: gather-aggregate own 8 nodes ----
    const int node = nbase + wave * 8 + g;
    if (node < n) {
        {   // write hq early so its registers retire before the gather
            const float4 hq = *(const float4*)&hin[(size_t)node * 32 + q * 4];
            *(float4*)&sagg[wave][g][64 + q * 4] = hq;
        }
        float4 aA = make_float4(0.f, 0.f, 0.f, 0.f);
        float4 aM = make_float4(0.f, 0.f, 0.f, 0.f);

        {
            const int rs = row_tp[node], d = deg_tp[node];
            for (int e = 0; e < d; e++) {
                const int j = col_tp[rs + e];
                const float4 v = *(const float4*)&hin[(size_t)j * 32 + q * 4];
                aA.x += v.x; aA.y += v.y; aA.z += v.z; aA.w += v.w;
            }
        }
        {
            const int rs = row_it[node], d = deg_it[node];
            int e = 0;
            for (; e + 3 < d; e += 4) {
                const int j0 = col_it[rs + e];
                const int j1 = col_it[rs + e + 1];
                const int j2 = col_it[rs + e + 2];
                const int j3 = col_it[rs + e + 3];
                const float4 v0 = *(const float4*)&hin[(size_t)j0 * 32 + q * 4];
                const float4 v1 = *(const float4*)&hin[(size_t)j1 * 32 + q * 4];
                const float4 v2 = *(const float4*)&hin[(size_t)j2 * 32 + q * 4];
                const float4 v3 = *(const float4*)&hin[(size_t)j3 * 32 + q * 4];
                aM.x += (v0.x + v1.x) + (v2.x + v3.x);
                aM.y += (v0.y + v1.y) + (v2.y + v3.y);
                aM.z += (v0.z + v1.z) + (v2.z + v3.z);
                aM.w += (v0.w + v1.w) + (v2.w + v3.w);
            }
            for (; e < d; e++) {
                const int j = col_it[rs + e];
                const float4 v = *(const float4*)&hin[(size_t)j * 32 + q * 4];
                aM.x += v.x; aM.y += v.y; aM.z += v.z; aM.w += v.w;
            }
        }

        const float ic = inv_cnt[node];
        aM.x *= ic; aM.y *= ic; aM.z *= ic; aM.w *= ic;
        *(float4*)&sagg[wave][g][q * 4]      = aA;
        *(float4*)&sagg[wave][g][32 + q * 4] = aM;
    }
    __syncthreads();   // cross-wave sagg reads below

    // ---- W tile load (after barrier: does not overlap gather registers) ----
    float w[24];
#pragma unroll
    for (int k = 0; k < 24; k++)
        w[k] = Wcat[(kq * 24 + k) * 32 + c];
    const float bc = bias[c];

    // ---- Phase 2: partials for all 16 block nodes (quarter kq per lane) ----
#pragma unroll
    for (int nd = 0; nd < 16; nd++) {
        if (nbase + nd < n) {
            const float* ap = &sagg[nd >> 3][nd & 7][kq * 24];
            float acc = 0.f;
#pragma unroll
            for (int kk = 0; kk < 24; kk += 4) {
                const float4 a4 = *(const float4*)(ap + kk);
                acc = fmaf(a4.x, w[kk],     acc);
                acc = fmaf(a4.y, w[kk + 1], acc);
                acc = fmaf(a4.z, w[kk + 2], acc);
                acc = fmaf(a4.w, w[kk + 3], acc);
            }
            acc += __shfl_xor(acc, 32, 64);    // combine kh halves of this wave
            if (kh == 0) part[wave][nd][c] = acc;
        }
    }
    __syncthreads();

    // ---- Finalize: wave w handles its own 8 nodes ----
    if (kh == 0) {
#pragma unroll
        for (int i = 0; i < 8; i++) {
            const int nd = wave * 8 + i;
            const int nn = nbase + nd;
            if (nn < n) {
                const float resid = sagg[wave][i][64 + c];
                const float r = fmaxf(part[0][nd][c] + part[1][nd][c] + bc + resid, 0.f);
                hout[(size_t)nn * 32 + c] = r;
            }
        }
    }
}

// ---------------- Aggregation (C=6, head): 8 nodes per wave ----------------

__global__ __launch_bounds__(256, 8) void agg6_kernel(
    int n, const float* __restrict__ hin,
    const int* __restrict__ row_it, const int* __restrict__ deg_it, const int* __restrict__ col_it,
    const int* __restrict__ row_tp, const int* __restrict__ deg_tp, const int* __restrict__ col_tp,
    const float* __restrict__ inv_cnt, float* __restrict__ agg)
{
    const int wave = threadIdx.x >> 6;
    const int lane = threadIdx.x & 63;
    const int g = lane >> 3;
    const int c = lane & 7;
    const int cc = (c < 6) ? c : 0;
    const int node = (blockIdx.x * 4 + wave) * 8 + g;
    if (node >= n) return;

    float aA = 0.f, aM = 0.f;
    {
        const int rs = row_tp[node], d = deg_tp[node];
        for (int e = 0; e < d; e++) {
            const int j = col_tp[rs + e];
            aA += hin[(size_t)j * 6 + cc];
        }
    }
    {
        const int rs = row_it[node], d = deg_it[node];
        int e = 0;
        for (; e + 3 < d; e += 4) {
            const int j0 = col_it[rs + e];
            const int j1 = col_it[rs + e + 1];
            const int j2 = col_it[rs + e + 2];
            const int j3 = col_it[rs + e + 3];
            aM += (hin[(size_t)j0 * 6 + cc] + hin[(size_t)j1 * 6 + cc])
                + (hin[(size_t)j2 * 6 + cc] + hin[(size_t)j3 * 6 + cc]);
        }
        for (; e < d; e++) {
            const int j = col_it[rs + e];
            aM += hin[(size_t)j * 6 + cc];
        }
    }

    if (c < 6) {
        agg[(size_t)node * 12 + c]     = aA;
        agg[(size_t)node * 12 + 6 + c] = aM * inv_cnt[node];
    }
}

// ---------------- Head GEMM (CI=6), register version ----------------

template <int CI, bool RESID>
__global__ __launch_bounds__(256) void gemm_reg_kernel(
    int n, const float* __restrict__ agg, const float* __restrict__ hin,
    const float* __restrict__ Wcat, const float* __restrict__ bias,
    float* __restrict__ hout)
{
    const int node = blockIdx.x * 256 + threadIdx.x;
    if (node >= n) return;

    float acc[32];
#pragma unroll
    for (int j = 0; j < 32; j++) acc[j] = bias[j];

    if constexpr (CI == 32) {
        const float* arow = agg + (size_t)node * 64;
#pragma unroll
        for (int c = 0; c < 8; c++) {
            const float4 a0 = *(const float4*)(arow + c * 8);
            const float4 a1 = *(const float4*)(arow + c * 8 + 4);
            const float av[8] = {a0.x, a0.y, a0.z, a0.w, a1.x, a1.y, a1.z, a1.w};
#pragma unroll
            for (int kk = 0; kk < 8; kk++) {
                const float* wr = Wcat + (c * 8 + kk) * 32;
#pragma unroll
                for (int j = 0; j < 32; j++) acc[j] = fmaf(av[kk], wr[j], acc[j]);
            }
        }
        const float* hrow = hin + (size_t)node * 32;
#pragma unroll
        for (int c = 0; c < 4; c++) {
            const float4 a0 = *(const float4*)(hrow + c * 8);
            const float4 a1 = *(const float4*)(hrow + c * 8 + 4);
            const float av[8] = {a0.x, a0.y, a0.z, a0.w, a1.x, a1.y, a1.z, a1.w};
#pragma unroll
            for (int kk = 0; kk < 8; kk++) {
                const float* wr = Wcat + (64 + c * 8 + kk) * 32;
#pragma unroll
                for (int j = 0; j < 32; j++) acc[j] = fmaf(av[kk], wr[j], acc[j]);
            }
            if (RESID) {
#pragma unroll
                for (int kk = 0; kk < 8; kk++) acc[c * 8 + kk] += av[kk];
            }
        }
    } else {  // CI == 6, K = 18
        const float* arow = agg + (size_t)node * 12;
#pragma unroll
        for (int k = 0; k < 12; k++) {
            const float a = arow[k];
            const float* wr = Wcat + k * 32;
#pragma unroll
            for (int j = 0; j < 32; j++) acc[j] = fmaf(a, wr[j], acc[j]);
        }
        const float* xrow = hin + (size_t)node * 6;
#pragma unroll
        for (int k = 0; k < 6; k++) {
            const float a = xrow[k];
            const float* wr = Wcat + (12 + k) * 32;
#pragma unroll
            for (int j = 0; j < 32; j++) acc[j] = fmaf(a, wr[j], acc[j]);
        }
    }

#pragma unroll
    for (int j = 0; j < 32; j++) acc[j] = fmaxf(acc[j], 0.f);
    float* orow = hout + (size_t)node * 32;
#pragma unroll
    for (int j = 0; j < 32; j += 4)
        *(float4*)(orow + j) = make_float4(acc[j], acc[j + 1], acc[j + 2], acc[j + 3]);
}

// ---------------- Final linear: W-in-registers, node-streaming ----------------

__global__ __launch_bounds__(256) void final_kernel(
    int n, const float* __restrict__ h, const float* __restrict__ Wout,
    const float* __restrict__ bout, float* __restrict__ out)
{
    const int wave = threadIdx.x >> 6;
    const int lane = threadIdx.x & 63;
    const int c2 = lane * 2;  // this lane's 2 output columns

    int node0 = (blockIdx.x * 4 + wave) * 32;
    if (node0 >= n) return;
    const int node_hi = min(node0 + 32, n);

    float2 w[32];
#pragma unroll
    for (int k = 0; k < 32; k++)
        w[k] = *(const float2*)(Wout + k * 128 + c2);
    const float2 bb = *(const float2*)(bout + c2);

    const float* hp = h + (size_t)node0 * 32 + lane;
    float hv = *hp;

    for (; node0 < node_hi; node0 += 2) {
        float hvn = 0.f;
        if (node0 + 2 < node_hi) hvn = hp[64];
        hp += 64;

        float a0 = bb.x, a1 = bb.y;
        float d0 = bb.x, d1 = bb.y;
#pragma unroll
        for (int k = 0; k < 32; k++) {
            const float sA = __uint_as_float(
                __builtin_amdgcn_readlane(__float_as_uint(hv), k));
            const float sB = __uint_as_float(
                __builtin_amdgcn_readlane(__float_as_uint(hv), 32 + k));
            a0 = fmaf(sA, w[k].x, a0);
            a1 = fmaf(sA, w[k].y, a1);
            d0 = fmaf(sB, w[k].x, d0);
            d1 = fmaf(sB, w[k].y, d1);
        }

        *(float2*)(out + (size_t)node0 * 128 + c2) = make_float2(a0, a1);
        if (node0 + 1 < n)
            *(float2*)(out + (size_t)(node0 + 1) * 128 + c2) = make_float2(d0, d1);
        hv = hvn;
    }
}

// ---------------- launch ----------------

extern "C" void kernel_launch(void* const* d_in, const int* in_sizes, int n_in,
                              void* d_out, int out_size, void* d_ws, size_t ws_size,
                              hipStream_t stream)
{
    const float* x      = (const float*)d_in[0];
    const int*   ei_tp  = (const int*)d_in[1];
    const int*   ei_it  = (const int*)d_in[2];
    const float* W0_rel  = (const float*)d_in[3];
    const float* W0_root = (const float*)d_in[4];
    const float* b0      = (const float*)d_in[5];
    const float* W_rel   = (const float*)d_in[6];
    const float* W_root  = (const float*)d_in[7];
    const float* b       = (const float*)d_in[8];
    const float* Wout    = (const float*)d_in[9];
    const float* bout    = (const float*)d_in[10];
    float* out = (float*)d_out;

    const int n    = in_sizes[0] / 6;
    const int E_tp = in_sizes[1] / 2;
    const int E_it = in_sizes[2] / 2;
    const int B    = (n + 1023) >> 10;

    float* h0      = (float*)d_ws;
    float* h1      = h0 + (size_t)n * 32;
    int*   deg_it  = (int*)(h1 + (size_t)n * 32);
    int*   row_it  = deg_it + n;
    float* inv_cnt = (float*)(row_it + n);
    int*   deg_tp  = (int*)(inv_cnt + n);
    int*   ctr     = deg_tp + n;
    int*   bcnt    = ctr + 1;
    int*   bbase   = bcnt + 256;
    int*   bcursor = bbase + 257;
    int*   row_tp  = bcursor + 256;
    int*   next_tp = row_tp + n;
    int*   col_it  = next_tp + n;
    int*   col_tp  = col_it + E_it;
    float* wcat    = (float*)(col_tp + E_tp);   // 13024 floats
    unsigned* ebuf = (unsigned*)d_out;
    float* aggbuf  = (float*)d_out;

    hipMemsetAsync(deg_tp, 0, (size_t)(n + 1 + 256) * sizeof(int), stream);

    prep_weights_kernel<<<51, 256, 0, stream>>>(W0_rel, W0_root, b0, W_rel, W_root, b, wcat);

    bucket_count_kernel<<<512, 256, 0, stream>>>(ei_it, E_it, B, bcnt);
    bucket_prefix_kernel<<<1, 256, 0, stream>>>(B, bcnt, bbase, bcursor);
    multisplit_kernel<<<(E_it + MS_E - 1) / MS_E, 256, 0, stream>>>(ei_it, E_it, bcursor, ebuf);
    csr_it_kernel<<<B, 256, 0, stream>>>(n, ebuf, bbase, row_it, deg_it, inv_cnt, col_it);

    hist_tp_kernel<<<(E_tp + 255) / 256, 256, 0, stream>>>(ei_tp, E_tp, deg_tp);
    alloc_tp_kernel<<<(n + 255) / 256, 256, 0, stream>>>(n, deg_tp, row_tp, next_tp, ctr);
    fill_tp_kernel<<<(E_tp + 255) / 256, 256, 0, stream>>>(ei_tp, E_tp, next_tp, col_tp);

    const int agg_blocks = (n + 31) / 32;

    agg6_kernel<<<agg_blocks, 256, 0, stream>>>(n, x, row_it, deg_it, col_it,
                                                row_tp, deg_tp, col_tp, inv_cnt, aggbuf);
    gemm_reg_kernel<6, false><<<(n + 255) / 256, 256, 0, stream>>>(
        n, aggbuf, x, wcat, wcat + 12864, h0);

    float* hin  = h0;
    float* hout = h1;
    for (int l = 0; l < 4; l++) {
        layer_fused_kernel<<<(n + 15) / 16, 128, 0, stream>>>(
            n, hin, row_it, deg_it, col_it, row_tp, deg_tp, col_tp, inv_cnt,
            wcat + 576 + l * 3072, wcat + 12896 + l * 32, hout);
        float* t = hin; hin = hout; hout = t;
    }

    final_kernel<<<(n + 127) / 128, 256, 0, stream>>>(n, hin, Wout, bout, out);
}

// Round 18
// 685.821 us; speedup vs baseline: 1.1027x; 1.0460x over previous
//
#include <hip/hip_runtime.h>

// n must be <= 256*1024 for the bucket scheme (bucket = dst >> 10, B <= 256)
// and for the 4B edge packing ((dst&1023)<<18 | src, src < 2^18).
// Hidden state h is stored as bf16 (storage only; all math in fp32).

__device__ __forceinline__ float bf2f_lo(unsigned u) {
    return __uint_as_float(u << 16);
}
__device__ __forceinline__ float bf2f_hi(unsigned u) {
    return __uint_as_float(u & 0xFFFF0000u);
}
__device__ __forceinline__ unsigned short f2bf(float f) {   // RTNE
    unsigned u = __float_as_uint(f);
    u += 0x7FFFu + ((u >> 16) & 1u);
    return (unsigned short)(u >> 16);
}

// ---------------- CSR build: tp (small, 200K edges) — old path ----------------

__global__ __launch_bounds__(256) void hist_tp_kernel(
    const int* __restrict__ ei_tp, int E_tp, int* __restrict__ deg_tp)
{
    int i = blockIdx.x * 256 + threadIdx.x;
    if (i < E_tp) atomicAdd(&deg_tp[ei_tp[E_tp + i]], 1);
}

__global__ __launch_bounds__(256) void alloc_tp_kernel(
    int n, const int* __restrict__ deg_tp,
    int* __restrict__ row_tp, int* __restrict__ next_tp, int* __restrict__ ctr)
{
    int i = blockIdx.x * 256 + threadIdx.x;
    if (i >= n) return;
    int d = deg_tp[i];
    int r = atomicAdd(&ctr[0], d);
    row_tp[i] = r; next_tp[i] = r;
}

__global__ __launch_bounds__(256) void fill_tp_kernel(
    const int* __restrict__ ei_tp, int E_tp,
    int* __restrict__ next_tp, int* __restrict__ col_tp)
{
    int i = blockIdx.x * 256 + threadIdx.x;
    if (i >= E_tp) return;
    int src = ei_tp[i];
    int dst = ei_tp[E_tp + i];
    col_tp[atomicAdd(&next_tp[dst], 1)] = src;
}

// ---------------- CSR build: it (3.2M edges) — two-level multisplit ----------------

__global__ __launch_bounds__(256) void bucket_count_kernel(
    const int* __restrict__ ei_it, int E_it, int B, int* __restrict__ bcnt)
{
    __shared__ int h[256];
    h[threadIdx.x] = 0;
    __syncthreads();
    const int stride = gridDim.x * 256;
    for (int i = blockIdx.x * 256 + threadIdx.x; i < E_it; i += stride)
        atomicAdd(&h[ei_it[E_it + i] >> 10], 1);
    __syncthreads();
    int v = h[threadIdx.x];
    if (threadIdx.x < B && v) atomicAdd(&bcnt[threadIdx.x], v);
}

__global__ __launch_bounds__(256) void bucket_prefix_kernel(
    int B, const int* __restrict__ bcnt, int* __restrict__ bbase, int* __restrict__ bcursor)
{
    __shared__ int s[256];
    const int t = threadIdx.x;
    s[t] = (t < B) ? bcnt[t] : 0;
    __syncthreads();
    for (int off = 1; off < 256; off <<= 1) {
        int v = (t >= off) ? s[t - off] : 0;
        __syncthreads();
        if (t >= off) s[t] += v;
        __syncthreads();
    }
    if (t == 0) bbase[0] = 0;
    if (t < B) {
        bbase[t + 1] = s[t];
        bcursor[t] = s[t] - bcnt[t];
    }
}

#define MS_E 4096

__global__ __launch_bounds__(256) void multisplit_kernel(
    const int* __restrict__ ei_it, int E_it,
    int* __restrict__ bcursor, unsigned* __restrict__ ebuf)
{
    __shared__ int cnt[256];
    __shared__ int lstart[256];
    __shared__ int gbase[256];
    __shared__ int lnext[256];
    __shared__ unsigned sbuf[MS_E];
    __shared__ unsigned char sbk[MS_E];

    const int t = threadIdx.x;
    const int base = blockIdx.x * MS_E;
    const int m = min(MS_E, E_it - base);

    cnt[t] = 0;
    __syncthreads();

    for (int i = t; i < m; i += 256)
        atomicAdd(&cnt[ei_it[E_it + base + i] >> 10], 1);
    __syncthreads();

    const int c = cnt[t];
    lnext[t] = c;
    __syncthreads();
    for (int off = 1; off < 256; off <<= 1) {
        int v = (t >= off) ? lnext[t - off] : 0;
        __syncthreads();
        if (t >= off) lnext[t] += v;
        __syncthreads();
    }
    const int ex = lnext[t] - c;
    lstart[t] = ex;
    if (c) gbase[t] = atomicAdd(&bcursor[t], c);
    lnext[t] = ex;
    __syncthreads();

    for (int i = t; i < m; i += 256) {
        const int src = ei_it[base + i];
        const int dst = ei_it[E_it + base + i];
        const int bk = dst >> 10;
        const int pos = atomicAdd(&lnext[bk], 1);
        sbuf[pos] = ((unsigned)(dst & 1023) << 18) | (unsigned)src;
        sbk[pos] = (unsigned char)bk;
    }
    __syncthreads();

    for (int i = t; i < m; i += 256) {
        const int bk = sbk[i];
        ebuf[gbase[bk] + (i - lstart[bk])] = sbuf[i];
    }
}

__global__ __launch_bounds__(256) void csr_it_kernel(
    int n, const unsigned* __restrict__ ebuf, const int* __restrict__ bbase,
    int* __restrict__ row_it, int* __restrict__ deg_it,
    float* __restrict__ inv_cnt, int* __restrict__ col_it)
{
    __shared__ int ldeg[1024];
    __shared__ int lnext[1024];
    __shared__ int lpart[256];
    const int b = blockIdx.x;
    const int t = threadIdx.x;
    const int node_lo = b << 10;
    const int nn = min(1024, n - node_lo);
    const int e0 = bbase[b], e1 = bbase[b + 1];

    for (int i = t; i < nn; i += 256) ldeg[i] = 0;
    __syncthreads();
    for (int i = e0 + t; i < e1; i += 256)
        atomicAdd(&ldeg[(int)(ebuf[i] >> 18)], 1);
    __syncthreads();

    const int i4 = 4 * t;
    int l0 = (i4     < nn) ? ldeg[i4]     : 0;
    int l1 = (i4 + 1 < nn) ? ldeg[i4 + 1] : 0;
    int l2 = (i4 + 2 < nn) ? ldeg[i4 + 2] : 0;
    int l3 = (i4 + 3 < nn) ? ldeg[i4 + 3] : 0;
    const int lsum = l0 + l1 + l2 + l3;
    lpart[t] = lsum;
    __syncthreads();
    for (int off = 1; off < 256; off <<= 1) {
        int v = (t >= off) ? lpart[t - off] : 0;
        __syncthreads();
        if (t >= off) lpart[t] += v;
        __syncthreads();
    }
    const int ex = lpart[t] - lsum;

    const int p[4] = {ex, ex + l0, ex + l0 + l1, ex + l0 + l1 + l2};
    const int l[4] = {l0, l1, l2, l3};
#pragma unroll
    for (int k = 0; k < 4; k++) {
        int i = i4 + k;
        if (i < nn) {
            lnext[i] = p[k];
            row_it[node_lo + i]  = e0 + p[k];
            deg_it[node_lo + i]  = l[k];
            inv_cnt[node_lo + i] = 1.0f / (float)max(l[k], 1);
        }
    }
    __syncthreads();
    for (int i = e0 + t; i < e1; i += 256) {
        const unsigned v = ebuf[i];
        const int dstl = (int)(v >> 18);
        const int pos  = atomicAdd(&lnext[dstl], 1);
        col_it[e0 + pos] = (int)(v & 0x3FFFFu);
    }
}

// ---------------- Weight prep: Wcat = [Wrel0 | Wrel1 | Wroot0+Wroot1], bias sums ----
// Layout (floats): head W 18x32 @ 0; layer l W 96x32 @ 576 + l*3072;
// head bias 32 @ 12864; layer l bias 32 @ 12896 + l*32. Total 13024.

__global__ __launch_bounds__(256) void prep_weights_kernel(
    const float* __restrict__ W0_rel, const float* __restrict__ W0_root,
    const float* __restrict__ b0, const float* __restrict__ W_rel,
    const float* __restrict__ W_root, const float* __restrict__ b,
    float* __restrict__ wcat)
{
    int i = blockIdx.x * 256 + threadIdx.x;
    if (i < 576) {
        int k = i >> 5, j = i & 31;
        float v;
        if (k < 6)       v = W0_rel[k * 32 + j];
        else if (k < 12) v = W0_rel[192 + (k - 6) * 32 + j];
        else             v = W0_root[(k - 12) * 32 + j] + W0_root[192 + (k - 12) * 32 + j];
        wcat[i] = v;
    } else if (i < 576 + 4 * 3072) {
        int t = i - 576;
        int l = t / 3072, r = t % 3072;
        int k = r >> 5, j = r & 31;
        const float* Wr = W_rel  + l * 2048;
        const float* Wt = W_root + l * 2048;
        float v;
        if (k < 32)      v = Wr[k * 32 + j];
        else if (k < 64) v = Wr[1024 + (k - 32) * 32 + j];
        else             v = Wt[(k - 64) * 32 + j] + Wt[1024 + (k - 64) * 32 + j];
        wcat[i] = v;
    } else if (i < 13024) {
        int t = i - 12864;
        if (t < 32) wcat[i] = b0[t] + b0[32 + t];
        else {
            int l = (t - 32) >> 5, j = (t - 32) & 31;
            wcat[i] = b[l * 64 + j] + b[l * 64 + 32 + j];
        }
    }
}

// ---------------- Fused layer (v4): bf16 h storage, fp32 math ----------------
// v3 (fp32) measured: occupancy 78%, FETCH 210MB, 2.88 TB/s, 83.5us —
// traffic-bound on the random 128B/node gather. v4 halves gather bytes:
// h stored bf16 (64B/node row). Loads convert via <<16; stores RTNE.
// Structure identical to v3: 128 thr, (128,6); phase 1 gather-aggregate into
// sagg[2][8][96] (fp32: aggA|aggM|hq); W tile w[24] loaded after barrier;
// phase 2 cross-wave 4-quarter GEMM -> part[2][16][32]; finalize own 8 nodes.

__global__ __launch_bounds__(128, 6) void layer_fused_kernel(
    int n, const unsigned short* __restrict__ hin,
    const int* __restrict__ row_it, const int* __restrict__ deg_it, const int* __restrict__ col_it,
    const int* __restrict__ row_tp, const int* __restrict__ deg_tp, const int* __restrict__ col_tp,
    const float* __restrict__ inv_cnt,
    const float* __restrict__ Wcat, const float* __restrict__ bias,
    unsigned short* __restrict__ hout)
{
    __shared__ __align__(16) float sagg[2][8][96];   // [wave][node][aggA|aggM|hq] 6144 B
    __shared__ float part[2][16][32];                // [wave][node][col] 4096 B

    const int wave = threadIdx.x >> 6;
    const int lane = threadIdx.x & 63;
    const int g = lane >> 3;
    const int q = lane & 7;
    const int c  = lane & 31;
    const int kh = lane >> 5;
    const int kq = wave * 2 + kh;          // k-quarter: rows [kq*24, kq*24+24)
    const int nbase = blockIdx.x * 16;     // block's 16 nodes
    if (nbase >= n) return;                // uniform across block

    // ---- Phase 1: gather-aggregate own 8 nodes ----
    const int node = nbase + wave * 8 + g;
    if (node < n) {
        {   // hq: 4 bf16 -> fp32, written to LDS immediately
            const uint2 hv = *(const uint2*)&hin[(size_t)node * 32 + q * 4];
            float4 hq;
            hq.x = bf2f_lo(hv.x); hq.y = bf2f_hi(hv.x);
            hq.z = bf2f_lo(hv.y); hq.w = bf2f_hi(hv.y);
            *(float4*)&sagg[wave][g][64 + q * 4] = hq;
        }
        float4 aA = make_float4(0.f, 0.f, 0.f, 0.f);
        float4 aM = make_float4(0.f, 0.f, 0.f, 0.f);

        {
            const int rs = row_tp[node], d = deg_tp[node];
            for (int e = 0; e < d; e++) {
                const int j = col_tp[rs + e];
                const uint2 v = *(const uint2*)&hin[(size_t)j * 32 + q * 4];
                aA.x += bf2f_lo(v.x); aA.y += bf2f_hi(v.x);
                aA.z += bf2f_lo(v.y); aA.w += bf2f_hi(v.y);
            }
        }
        {
            const int rs = row_it[node], d = deg_it[node];
            int e = 0;
            for (; e + 3 < d; e += 4) {
                const int j0 = col_it[rs + e];
                const int j1 = col_it[rs + e + 1];
                const int j2 = col_it[rs + e + 2];
                const int j3 = col_it[rs + e + 3];
                const uint2 v0 = *(const uint2*)&hin[(size_t)j0 * 32 + q * 4];
                const uint2 v1 = *(const uint2*)&hin[(size_t)j1 * 32 + q * 4];
                const uint2 v2 = *(const uint2*)&hin[(size_t)j2 * 32 + q * 4];
                const uint2 v3 = *(const uint2*)&hin[(size_t)j3 * 32 + q * 4];
                aM.x += (bf2f_lo(v0.x) + bf2f_lo(v1.x)) + (bf2f_lo(v2.x) + bf2f_lo(v3.x));
                aM.y += (bf2f_hi(v0.x) + bf2f_hi(v1.x)) + (bf2f_hi(v2.x) + bf2f_hi(v3.x));
                aM.z += (bf2f_lo(v0.y) + bf2f_lo(v1.y)) + (bf2f_lo(v2.y) + bf2f_lo(v3.y));
                aM.w += (bf2f_hi(v0.y) + bf2f_hi(v1.y)) + (bf2f_hi(v2.y) + bf2f_hi(v3.y));
            }
            for (; e < d; e++) {
                const int j = col_it[rs + e];
                const uint2 v = *(const uint2*)&hin[(size_t)j * 32 + q * 4];
                aM.x += bf2f_lo(v.x); aM.y += bf2f_hi(v.x);
                aM.z += bf2f_lo(v.y); aM.w += bf2f_hi(v.y);
            }
        }

        const float ic = inv_cnt[node];
        aM.x *= ic; aM.y *= ic; aM.z *= ic; aM.w *= ic;
        *(float4*)&sagg[wave][g][q * 4]      = aA;
        *(float4*)&sagg[wave][g][32 + q * 4] = aM;
    }
    __syncthreads();   // cross-wave sagg reads below

    // ---- W tile load (after barrier: does not overlap gather registers) ----
    float w[24];
#pragma unroll
    for (int k = 0; k < 24; k++)
        w[k] = Wcat[(kq * 24 + k) * 32 + c];
    const float bc = bias[c];

    // ---- Phase 2: partials for all 16 block nodes (quarter kq per lane) ----
#pragma unroll
    for (int nd = 0; nd < 16; nd++) {
        if (nbase + nd < n) {
            const float* ap = &sagg[nd >> 3][nd & 7][kq * 24];
            float acc = 0.f;
#pragma unroll
            for (int kk = 0; kk < 24; kk += 4) {
                const float4 a4 = *(const float4*)(ap + kk);
                acc = fmaf(a4.x, w[kk],     acc);
                acc = fmaf(a4.y, w[kk + 1], acc);
                acc = fmaf(a4.z, w[kk + 2], acc);
                acc = fmaf(a4.w, w[kk + 3], acc);
            }
            acc += __shfl_xor(acc, 32, 64);    // combine kh halves of this wave
            if (kh == 0) part[wave][nd][c] = acc;
        }
    }
    __syncthreads();

    // ---- Finalize: wave w handles its own 8 nodes ----
    if (kh == 0) {
#pragma unroll
        for (int i = 0; i < 8; i++) {
            const int nd = wave * 8 + i;
            const int nn = nbase + nd;
            if (nn < n) {
                const float resid = sagg[wave][i][64 + c];
                const float r = fmaxf(part[0][nd][c] + part[1][nd][c] + bc + resid, 0.f);
                hout[(size_t)nn * 32 + c] = f2bf(r);
            }
        }
    }
}

// ---------------- Aggregation (C=6, head): 8 nodes per wave ----------------

__global__ __launch_bounds__(256, 8) void agg6_kernel(
    int n, const float* __restrict__ hin,
    const int* __restrict__ row_it, const int* __restrict__ deg_it, const int* __restrict__ col_it,
    const int* __restrict__ row_tp, const int* __restrict__ deg_tp, const int* __restrict__ col_tp,
    const float* __restrict__ inv_cnt, float* __restrict__ agg)
{
    const int wave = threadIdx.x >> 6;
    const int lane = threadIdx.x & 63;
    const int g = lane >> 3;
    const int c = lane & 7;
    const int cc = (c < 6) ? c : 0;
    const int node = (blockIdx.x * 4 + wave) * 8 + g;
    if (node >= n) return;

    float aA = 0.f, aM = 0.f;
    {
        const int rs = row_tp[node], d = deg_tp[node];
        for (int e = 0; e < d; e++) {
            const int j = col_tp[rs + e];
            aA += hin[(size_t)j * 6 + cc];
        }
    }
    {
        const int rs = row_it[node], d = deg_it[node];
        int e = 0;
        for (; e + 3 < d; e += 4) {
            const int j0 = col_it[rs + e];
            const int j1 = col_it[rs + e + 1];
            const int j2 = col_it[rs + e + 2];
            const int j3 = col_it[rs + e + 3];
            aM += (hin[(size_t)j0 * 6 + cc] + hin[(size_t)j1 * 6 + cc])
                + (hin[(size_t)j2 * 6 + cc] + hin[(size_t)j3 * 6 + cc]);
        }
        for (; e < d; e++) {
            const int j = col_it[rs + e];
            aM += hin[(size_t)j * 6 + cc];
        }
    }

    if (c < 6) {
        agg[(size_t)node * 12 + c]     = aA;
        agg[(size_t)node * 12 + 6 + c] = aM * inv_cnt[node];
    }
}

// ---------------- Head GEMM (CI=6 -> 32), writes bf16 h ----------------

__global__ __launch_bounds__(256) void gemm6_kernel(
    int n, const float* __restrict__ agg, const float* __restrict__ xin,
    const float* __restrict__ Wcat, const float* __restrict__ bias,
    unsigned short* __restrict__ hout)
{
    const int node = blockIdx.x * 256 + threadIdx.x;
    if (node >= n) return;

    float acc[32];
#pragma unroll
    for (int j = 0; j < 32; j++) acc[j] = bias[j];

    const float* arow = agg + (size_t)node * 12;
#pragma unroll
    for (int k = 0; k < 12; k++) {
        const float a = arow[k];
        const float* wr = Wcat + k * 32;
#pragma unroll
        for (int j = 0; j < 32; j++) acc[j] = fmaf(a, wr[j], acc[j]);
    }
    const float* xrow = xin + (size_t)node * 6;
#pragma unroll
    for (int k = 0; k < 6; k++) {
        const float a = xrow[k];
        const float* wr = Wcat + (12 + k) * 32;
#pragma unroll
        for (int j = 0; j < 32; j++) acc[j] = fmaf(a, wr[j], acc[j]);
    }

    unsigned pk[16];
#pragma unroll
    for (int j = 0; j < 16; j++) {
        const float r0 = fmaxf(acc[2 * j],     0.f);
        const float r1 = fmaxf(acc[2 * j + 1], 0.f);
        pk[j] = (unsigned)f2bf(r0) | ((unsigned)f2bf(r1) << 16);
    }
    unsigned* orow = (unsigned*)(hout + (size_t)node * 32);
#pragma unroll
    for (int j = 0; j < 16; j += 4)
        *(uint4*)(orow + j) = make_uint4(pk[j], pk[j + 1], pk[j + 2], pk[j + 3]);
}

// ---------------- Final linear: W-in-registers, node-streaming, bf16 h ----------------

__global__ __launch_bounds__(256) void final_kernel(
    int n, const unsigned short* __restrict__ h, const float* __restrict__ Wout,
    const float* __restrict__ bout, float* __restrict__ out)
{
    const int wave = threadIdx.x >> 6;
    const int lane = threadIdx.x & 63;
    const int c2 = lane * 2;  // this lane's 2 output columns

    int node0 = (blockIdx.x * 4 + wave) * 32;
    if (node0 >= n) return;
    const int node_hi = min(node0 + 32, n);

    float2 w[32];
#pragma unroll
    for (int k = 0; k < 32; k++)
        w[k] = *(const float2*)(Wout + k * 128 + c2);
    const float2 bb = *(const float2*)(bout + c2);

    // lane k holds h[nodeA][k] (k<32) or h[nodeB][k-32]; 64 lanes x 2B = 128B
    const unsigned short* hp = h + (size_t)node0 * 32 + lane;
    float hv = __uint_as_float((unsigned)hp[0] << 16);

    for (; node0 < node_hi; node0 += 2) {
        float hvn = 0.f;
        if (node0 + 2 < node_hi)
            hvn = __uint_as_float((unsigned)hp[64] << 16);
        hp += 64;

        float a0 = bb.x, a1 = bb.y;
        float d0 = bb.x, d1 = bb.y;
#pragma unroll
        for (int k = 0; k < 32; k++) {
            const float sA = __uint_as_float(
                __builtin_amdgcn_readlane(__float_as_uint(hv), k));
            const float sB = __uint_as_float(
                __builtin_amdgcn_readlane(__float_as_uint(hv), 32 + k));
            a0 = fmaf(sA, w[k].x, a0);
            a1 = fmaf(sA, w[k].y, a1);
            d0 = fmaf(sB, w[k].x, d0);
            d1 = fmaf(sB, w[k].y, d1);
        }

        *(float2*)(out + (size_t)node0 * 128 + c2) = make_float2(a0, a1);
        if (node0 + 1 < n)
            *(float2*)(out + (size_t)(node0 + 1) * 128 + c2) = make_float2(d0, d1);
        hv = hvn;
    }
}

// ---------------- launch ----------------

extern "C" void kernel_launch(void* const* d_in, const int* in_sizes, int n_in,
                              void* d_out, int out_size, void* d_ws, size_t ws_size,
                              hipStream_t stream)
{
    const float* x      = (const float*)d_in[0];
    const int*   ei_tp  = (const int*)d_in[1];
    const int*   ei_it  = (const int*)d_in[2];
    const float* W0_rel  = (const float*)d_in[3];
    const float* W0_root = (const float*)d_in[4];
    const float* b0      = (const float*)d_in[5];
    const float* W_rel   = (const float*)d_in[6];
    const float* W_root  = (const float*)d_in[7];
    const float* b       = (const float*)d_in[8];
    const float* Wout    = (const float*)d_in[9];
    const float* bout    = (const float*)d_in[10];
    float* out = (float*)d_out;

    const int n    = in_sizes[0] / 6;
    const int E_tp = in_sizes[1] / 2;
    const int E_it = in_sizes[2] / 2;
    const int B    = (n + 1023) >> 10;

    // h stored bf16: n*32 ushorts each (n*64 B)
    unsigned short* h0 = (unsigned short*)d_ws;
    unsigned short* h1 = h0 + (size_t)n * 32;
    int*   deg_it  = (int*)(h1 + (size_t)n * 32);
    int*   row_it  = deg_it + n;
    float* inv_cnt = (float*)(row_it + n);
    int*   deg_tp  = (int*)(inv_cnt + n);
    int*   ctr     = deg_tp + n;
    int*   bcnt    = ctr + 1;
    int*   bbase   = bcnt + 256;
    int*   bcursor = bbase + 257;
    int*   row_tp  = bcursor + 256;
    int*   next_tp = row_tp + n;
    int*   col_it  = next_tp + n;
    int*   col_tp  = col_it + E_it;
    float* wcat    = (float*)(col_tp + E_tp);   // 13024 floats
    unsigned* ebuf = (unsigned*)d_out;
    float* aggbuf  = (float*)d_out;

    hipMemsetAsync(deg_tp, 0, (size_t)(n + 1 + 256) * sizeof(int), stream);

    prep_weights_kernel<<<51, 256, 0, stream>>>(W0_rel, W0_root, b0, W_rel, W_root, b, wcat);

    bucket_count_kernel<<<512, 256, 0, stream>>>(ei_it, E_it, B, bcnt);
    bucket_prefix_kernel<<<1, 256, 0, stream>>>(B, bcnt, bbase, bcursor);
    multisplit_kernel<<<(E_it + MS_E - 1) / MS_E, 256, 0, stream>>>(ei_it, E_it, bcursor, ebuf);
    csr_it_kernel<<<B, 256, 0, stream>>>(n, ebuf, bbase, row_it, deg_it, inv_cnt, col_it);

    hist_tp_kernel<<<(E_tp + 255) / 256, 256, 0, stream>>>(ei_tp, E_tp, deg_tp);
    alloc_tp_kernel<<<(n + 255) / 256, 256, 0, stream>>>(n, deg_tp, row_tp, next_tp, ctr);
    fill_tp_kernel<<<(E_tp + 255) / 256, 256, 0, stream>>>(ei_tp, E_tp, next_tp, col_tp);

    const int agg_blocks = (n + 31) / 32;

    agg6_kernel<<<agg_blocks, 256, 0, stream>>>(n, x, row_it, deg_it, col_it,
                                                row_tp, deg_tp, col_tp, inv_cnt, aggbuf);
    gemm6_kernel<<<(n + 255) / 256, 256, 0, stream>>>(
        n, aggbuf, x, wcat, wcat + 12864, h0);

    unsigned short* hin  = h0;
    unsigned short* hout = h1;
    for (int l = 0; l < 4; l++) {
        layer_fused_kernel<<<(n + 15) / 16, 128, 0, stream>>>(
            n, hin, row_it, deg_it, col_it, row_tp, deg_tp, col_tp, inv_cnt,
            wcat + 576 + l * 3072, wcat + 12896 + l * 32, hout);
        unsigned short* t = hin; hin = hout; hout = t;
    }

    final_kernel<<<(n + 127) / 128, 256, 0, stream>>>(n, hin, Wout, bout, out);
}